// Round 10
// baseline (715.079 us; speedup 1.0000x reference)
//
#include <hip/hip_runtime.h>

#define LN_EPS 1e-5f
#define UPAD 292   // u row stride (floats)

// ---- CSR build: histogram of tgt ----
__global__ __launch_bounds__(256) void hist_tgt(
    const int* __restrict__ tgt, int* __restrict__ cnt, int E) {
  int e = blockIdx.x * 256 + threadIdx.x;
  if (e < E) atomicAdd(&cnt[tgt[e]], 1);
}

// ---- CSR build: exclusive scan over cnt -> rowptr (single block) ----
__global__ __launch_bounds__(1024) void scan_rowptr(
    const int* __restrict__ cnt, int* __restrict__ rowptr, int N) {
  __shared__ int part[1024];
  int tid = threadIdx.x;
  int per = (N + 1023) / 1024;
  int start = tid * per;
  int end = min(start + per, N);
  int s = 0;
  for (int i = start; i < end; ++i) s += cnt[i];
  part[tid] = s;
  __syncthreads();
  for (int off = 1; off < 1024; off <<= 1) {
    int v = (tid >= off) ? part[tid - off] : 0;
    __syncthreads();
    part[tid] += v;
    __syncthreads();
  }
  int excl = (tid == 0) ? 0 : part[tid - 1];
  for (int i = start; i < end; ++i) {
    rowptr[i] = excl;
    excl += cnt[i];
  }
  if (tid == 1023) rowptr[N] = excl;
}

// ---- CSR build: fill (src, eid) pairs ----
__global__ __launch_bounds__(256) void fill_csr(
    const int* __restrict__ src, const int* __restrict__ tgt,
    const int* __restrict__ rowptr, int* __restrict__ cur,
    int2* __restrict__ csr, int E) {
  int e = blockIdx.x * 256 + threadIdx.x;
  if (e >= E) return;
  int t = tgt[e];
  int pos = atomicAdd(&cur[t], 1);
  csr[rowptr[t] + pos] = make_int2(src[e], e);
}

// ---- gather-aggregate layer 0: one wave per node, float4/lane, 2 edges per
// wave-instruction (lane<32 even edge, lane>=32 odd edge), 8-pair unroll ----
__global__ __launch_bounds__(256) void agg0(
    const float* __restrict__ x, const float* __restrict__ ef,
    const int* __restrict__ rowptr, const int2* __restrict__ csr,
    float* __restrict__ SX, float* __restrict__ SE,
    float* __restrict__ degF, int N) {
  int n = blockIdx.x * 4 + (threadIdx.x >> 6);
  if (n >= N) return;
  int lane = threadIdx.x & 63;
  int half = lane >> 5;        // 0: even edges, 1: odd edges
  int fg = lane & 31;          // feature group
  int fl = fg * 4;             // float4 offset into 128-wide row
  bool efl = fg < 4;           // lanes covering the 16-wide ef row
  int b = rowptr[n], e = rowptr[n + 1];
  int d = e - b;
  float4 acc  = make_float4(0.f, 0.f, 0.f, 0.f);
  float4 acce = make_float4(0.f, 0.f, 0.f, 0.f);
  int pairs = d >> 1;
  int i = b + half;
  int t = 0;
  for (; t + 8 <= pairs; t += 8, i += 16) {
    int2 p0 = csr[i],      p1 = csr[i + 2],  p2 = csr[i + 4],  p3 = csr[i + 6];
    int2 p4 = csr[i + 8],  p5 = csr[i + 10], p6 = csr[i + 12], p7 = csr[i + 14];
    float4 v0 = *(const float4*)&x[(size_t)p0.x * 128 + fl];
    float4 v1 = *(const float4*)&x[(size_t)p1.x * 128 + fl];
    float4 v2 = *(const float4*)&x[(size_t)p2.x * 128 + fl];
    float4 v3 = *(const float4*)&x[(size_t)p3.x * 128 + fl];
    float4 v4 = *(const float4*)&x[(size_t)p4.x * 128 + fl];
    float4 v5 = *(const float4*)&x[(size_t)p5.x * 128 + fl];
    float4 v6 = *(const float4*)&x[(size_t)p6.x * 128 + fl];
    float4 v7 = *(const float4*)&x[(size_t)p7.x * 128 + fl];
    acc.x += ((v0.x + v1.x) + (v2.x + v3.x)) + ((v4.x + v5.x) + (v6.x + v7.x));
    acc.y += ((v0.y + v1.y) + (v2.y + v3.y)) + ((v4.y + v5.y) + (v6.y + v7.y));
    acc.z += ((v0.z + v1.z) + (v2.z + v3.z)) + ((v4.z + v5.z) + (v6.z + v7.z));
    acc.w += ((v0.w + v1.w) + (v2.w + v3.w)) + ((v4.w + v5.w) + (v6.w + v7.w));
    if (efl) {
      float4 e0 = *(const float4*)&ef[(size_t)p0.y * 16 + fl];
      float4 e1 = *(const float4*)&ef[(size_t)p1.y * 16 + fl];
      float4 e2 = *(const float4*)&ef[(size_t)p2.y * 16 + fl];
      float4 e3 = *(const float4*)&ef[(size_t)p3.y * 16 + fl];
      float4 e4 = *(const float4*)&ef[(size_t)p4.y * 16 + fl];
      float4 e5 = *(const float4*)&ef[(size_t)p5.y * 16 + fl];
      float4 e6 = *(const float4*)&ef[(size_t)p6.y * 16 + fl];
      float4 e7 = *(const float4*)&ef[(size_t)p7.y * 16 + fl];
      acce.x += ((e0.x + e1.x) + (e2.x + e3.x)) + ((e4.x + e5.x) + (e6.x + e7.x));
      acce.y += ((e0.y + e1.y) + (e2.y + e3.y)) + ((e4.y + e5.y) + (e6.y + e7.y));
      acce.z += ((e0.z + e1.z) + (e2.z + e3.z)) + ((e4.z + e5.z) + (e6.z + e7.z));
      acce.w += ((e0.w + e1.w) + (e2.w + e3.w)) + ((e4.w + e5.w) + (e6.w + e7.w));
    }
  }
  for (; t + 2 <= pairs; t += 2, i += 4) {
    int2 p0 = csr[i], p1 = csr[i + 2];
    float4 v0 = *(const float4*)&x[(size_t)p0.x * 128 + fl];
    float4 v1 = *(const float4*)&x[(size_t)p1.x * 128 + fl];
    acc.x += v0.x + v1.x; acc.y += v0.y + v1.y;
    acc.z += v0.z + v1.z; acc.w += v0.w + v1.w;
    if (efl) {
      float4 e0 = *(const float4*)&ef[(size_t)p0.y * 16 + fl];
      float4 e1 = *(const float4*)&ef[(size_t)p1.y * 16 + fl];
      acce.x += e0.x + e1.x; acce.y += e0.y + e1.y;
      acce.z += e0.z + e1.z; acce.w += e0.w + e1.w;
    }
  }
  for (; t < pairs; ++t, i += 2) {
    int2 p = csr[i];
    float4 v = *(const float4*)&x[(size_t)p.x * 128 + fl];
    acc.x += v.x; acc.y += v.y; acc.z += v.z; acc.w += v.w;
    if (efl) {
      float4 ev = *(const float4*)&ef[(size_t)p.y * 16 + fl];
      acce.x += ev.x; acce.y += ev.y; acce.z += ev.z; acce.w += ev.w;
    }
  }
  if ((d & 1) && half == 0) {
    int2 p = csr[e - 1];
    float4 v = *(const float4*)&x[(size_t)p.x * 128 + fl];
    acc.x += v.x; acc.y += v.y; acc.z += v.z; acc.w += v.w;
    if (efl) {
      float4 ev = *(const float4*)&ef[(size_t)p.y * 16 + fl];
      acce.x += ev.x; acce.y += ev.y; acce.z += ev.z; acce.w += ev.w;
    }
  }
  // combine even/odd halves
  acc.x += __shfl_xor(acc.x, 32);
  acc.y += __shfl_xor(acc.y, 32);
  acc.z += __shfl_xor(acc.z, 32);
  acc.w += __shfl_xor(acc.w, 32);
  acce.x += __shfl_xor(acce.x, 32);
  acce.y += __shfl_xor(acce.y, 32);
  acce.z += __shfl_xor(acce.z, 32);
  acce.w += __shfl_xor(acce.w, 32);
  if (half == 0) {
    *(float4*)&SX[(size_t)n * 128 + fl] = acc;
    if (efl) *(float4*)&SE[(size_t)n * 16 + fl] = acce;
    if (lane == 0) degF[n] = (float)d;
  }
}

// ---- gather-aggregate layer 1: SH[n] = sum h[src], same paired-row scheme ----
__global__ __launch_bounds__(256) void agg1(
    const float* __restrict__ h, const int* __restrict__ rowptr,
    const int2* __restrict__ csr, float* __restrict__ SH, int N) {
  int n = blockIdx.x * 4 + (threadIdx.x >> 6);
  if (n >= N) return;
  int lane = threadIdx.x & 63;
  int half = lane >> 5;
  int fl = (lane & 31) * 4;
  int b = rowptr[n], e = rowptr[n + 1];
  int d = e - b;
  float4 acc = make_float4(0.f, 0.f, 0.f, 0.f);
  int pairs = d >> 1;
  int i = b + half;
  int t = 0;
  for (; t + 8 <= pairs; t += 8, i += 16) {
    int2 p0 = csr[i],      p1 = csr[i + 2],  p2 = csr[i + 4],  p3 = csr[i + 6];
    int2 p4 = csr[i + 8],  p5 = csr[i + 10], p6 = csr[i + 12], p7 = csr[i + 14];
    float4 v0 = *(const float4*)&h[(size_t)p0.x * 128 + fl];
    float4 v1 = *(const float4*)&h[(size_t)p1.x * 128 + fl];
    float4 v2 = *(const float4*)&h[(size_t)p2.x * 128 + fl];
    float4 v3 = *(const float4*)&h[(size_t)p3.x * 128 + fl];
    float4 v4 = *(const float4*)&h[(size_t)p4.x * 128 + fl];
    float4 v5 = *(const float4*)&h[(size_t)p5.x * 128 + fl];
    float4 v6 = *(const float4*)&h[(size_t)p6.x * 128 + fl];
    float4 v7 = *(const float4*)&h[(size_t)p7.x * 128 + fl];
    acc.x += ((v0.x + v1.x) + (v2.x + v3.x)) + ((v4.x + v5.x) + (v6.x + v7.x));
    acc.y += ((v0.y + v1.y) + (v2.y + v3.y)) + ((v4.y + v5.y) + (v6.y + v7.y));
    acc.z += ((v0.z + v1.z) + (v2.z + v3.z)) + ((v4.z + v5.z) + (v6.z + v7.z));
    acc.w += ((v0.w + v1.w) + (v2.w + v3.w)) + ((v4.w + v5.w) + (v6.w + v7.w));
  }
  for (; t + 2 <= pairs; t += 2, i += 4) {
    int2 p0 = csr[i], p1 = csr[i + 2];
    float4 v0 = *(const float4*)&h[(size_t)p0.x * 128 + fl];
    float4 v1 = *(const float4*)&h[(size_t)p1.x * 128 + fl];
    acc.x += v0.x + v1.x; acc.y += v0.y + v1.y;
    acc.z += v0.z + v1.z; acc.w += v0.w + v1.w;
  }
  for (; t < pairs; ++t, i += 2) {
    int2 p = csr[i];
    float4 v = *(const float4*)&h[(size_t)p.x * 128 + fl];
    acc.x += v.x; acc.y += v.y; acc.z += v.z; acc.w += v.w;
  }
  if ((d & 1) && half == 0) {
    int2 p = csr[e - 1];
    float4 v = *(const float4*)&h[(size_t)p.x * 128 + fl];
    acc.x += v.x; acc.y += v.y; acc.z += v.z; acc.w += v.w;
  }
  acc.x += __shfl_xor(acc.x, 32);
  acc.y += __shfl_xor(acc.y, 32);
  acc.z += __shfl_xor(acc.z, 32);
  acc.w += __shfl_xor(acc.w, 32);
  if (half == 0)
    *(float4*)&SH[(size_t)n * 128 + fl] = acc;
}

// ---- layer 0 GEMM: [32 nodes x 272] @ [272 x 128] + bias + LN + ReLU ----
// 512 threads (8 waves) over a 32-node tile: 2 nodes x 4 feats per thread.
// Weights direct from global, barrier-free K-loop.
__global__ __launch_bounds__(512, 6) void layer0_gemm(
    const float* __restrict__ x, const float* __restrict__ SX,
    const float* __restrict__ SE, const float* __restrict__ deg,
    const float* __restrict__ Ws, const float* __restrict__ Wm,
    const float* __restrict__ bs, const float* __restrict__ bm,
    const float* __restrict__ gam, const float* __restrict__ bet,
    float* __restrict__ h, int N) {
  __shared__ float u[32][UPAD];
  __shared__ float dgs[32], dinv[32];
  int tid = threadIdx.x;
  int n0 = blockIdx.x * 32;
  if (tid < 32) {
    int n = n0 + tid;
    float dg = (n < N) ? deg[n] : 0.f;
    dgs[tid] = dg;
    dinv[tid] = dg > 0.f ? 1.f / dg : 0.f;
  }
  __syncthreads();
  // stage u: x | SX/deg | SE/deg (float4 vectorized)
  for (int idx = tid; idx < 1024; idx += 512) {
    int m = idx >> 5, f = (idx & 31) * 4;
    int n = n0 + m;
    float4 xv = make_float4(0.f, 0.f, 0.f, 0.f), sv = xv;
    if (n < N) {
      xv = *(const float4*)&x[(size_t)n * 128 + f];
      sv = *(const float4*)&SX[(size_t)n * 128 + f];
      float di = dinv[m];
      sv.x *= di; sv.y *= di; sv.z *= di; sv.w *= di;
    }
    *(float4*)&u[m][f] = xv;
    *(float4*)&u[m][128 + f] = sv;
  }
  if (tid < 128) {
    int m = tid >> 2, f = (tid & 3) * 4;
    int n = n0 + m;
    float4 ev = make_float4(0.f, 0.f, 0.f, 0.f);
    if (n < N) {
      ev = *(const float4*)&SE[(size_t)n * 16 + f];
      float di = dinv[m];
      ev.x *= di; ev.y *= di; ev.z *= di; ev.w *= di;
    }
    *(float4*)&u[m][256 + f] = ev;
  }
  __syncthreads();

  int tn = tid >> 5;   // 0..15: node pair
  int tj = tid & 31;   // feature group
  int jb = tj * 4;
  float4 bsv = *(const float4*)&bs[jb];
  float4 bmv = *(const float4*)&bm[jb];
  float acc[2][4];
  #pragma unroll
  for (int m = 0; m < 2; ++m) {
    bool has = dgs[tn * 2 + m] > 0.f;
    acc[m][0] = bsv.x + (has ? bmv.x : 0.f);
    acc[m][1] = bsv.y + (has ? bmv.y : 0.f);
    acc[m][2] = bsv.z + (has ? bmv.z : 0.f);
    acc[m][3] = bsv.w + (has ? bmv.w : 0.f);
  }

  // k-loop part 1: Ws over u[:,0:128]
  #pragma unroll 2
  for (int k = 0; k < 128; k += 4) {
    float4 wv[4], uv[2];
    #pragma unroll
    for (int t = 0; t < 4; ++t) wv[t] = *(const float4*)&Ws[(size_t)(k + t) * 128 + jb];
    #pragma unroll
    for (int m = 0; m < 2; ++m) uv[m] = *(const float4*)&u[tn * 2 + m][k];
    #pragma unroll
    for (int m = 0; m < 2; ++m) {
      float us[4] = {uv[m].x, uv[m].y, uv[m].z, uv[m].w};
      #pragma unroll
      for (int t = 0; t < 4; ++t) {
        acc[m][0] = fmaf(us[t], wv[t].x, acc[m][0]);
        acc[m][1] = fmaf(us[t], wv[t].y, acc[m][1]);
        acc[m][2] = fmaf(us[t], wv[t].z, acc[m][2]);
        acc[m][3] = fmaf(us[t], wv[t].w, acc[m][3]);
      }
    }
  }
  // k-loop part 2: Wm over u[:,128:272]
  #pragma unroll 2
  for (int k = 0; k < 144; k += 4) {
    float4 wv[4], uv[2];
    #pragma unroll
    for (int t = 0; t < 4; ++t) wv[t] = *(const float4*)&Wm[(size_t)(k + t) * 128 + jb];
    #pragma unroll
    for (int m = 0; m < 2; ++m) uv[m] = *(const float4*)&u[tn * 2 + m][128 + k];
    #pragma unroll
    for (int m = 0; m < 2; ++m) {
      float us[4] = {uv[m].x, uv[m].y, uv[m].z, uv[m].w};
      #pragma unroll
      for (int t = 0; t < 4; ++t) {
        acc[m][0] = fmaf(us[t], wv[t].x, acc[m][0]);
        acc[m][1] = fmaf(us[t], wv[t].y, acc[m][1]);
        acc[m][2] = fmaf(us[t], wv[t].z, acc[m][2]);
        acc[m][3] = fmaf(us[t], wv[t].w, acc[m][3]);
      }
    }
  }

  __syncthreads();
  #pragma unroll
  for (int m = 0; m < 2; ++m)
    *(float4*)&u[tn * 2 + m][jb] = make_float4(acc[m][0], acc[m][1], acc[m][2], acc[m][3]);
  __syncthreads();

  // LN + ReLU: 16 threads per node, 8 feats each
  int node = tid >> 4, s = tid & 15;
  int fb = s * 8;
  float4 v0 = *(const float4*)&u[node][fb];
  float4 v1 = *(const float4*)&u[node][fb + 4];
  float sum = v0.x + v0.y + v0.z + v0.w + v1.x + v1.y + v1.z + v1.w;
  float sq  = v0.x*v0.x + v0.y*v0.y + v0.z*v0.z + v0.w*v0.w
            + v1.x*v1.x + v1.y*v1.y + v1.z*v1.z + v1.w*v1.w;
  #pragma unroll
  for (int off = 1; off < 16; off <<= 1) {
    sum += __shfl_xor(sum, off);
    sq  += __shfl_xor(sq, off);
  }
  float mean = sum * (1.f / 128.f);
  float var  = sq * (1.f / 128.f) - mean * mean;
  float rstd = rsqrtf(var + LN_EPS);
  int n = n0 + node;
  if (n < N) {
    float4 ga0 = *(const float4*)&gam[fb], ga1 = *(const float4*)&gam[fb + 4];
    float4 be0 = *(const float4*)&bet[fb], be1 = *(const float4*)&bet[fb + 4];
    float* hp = &h[(size_t)n * 128 + fb];
    float4 o;
    o.x = fmaxf((v0.x - mean) * rstd * ga0.x + be0.x, 0.f);
    o.y = fmaxf((v0.y - mean) * rstd * ga0.y + be0.y, 0.f);
    o.z = fmaxf((v0.z - mean) * rstd * ga0.z + be0.z, 0.f);
    o.w = fmaxf((v0.w - mean) * rstd * ga0.w + be0.w, 0.f);
    *(float4*)(hp + 0) = o;
    o.x = fmaxf((v1.x - mean) * rstd * ga1.x + be1.x, 0.f);
    o.y = fmaxf((v1.y - mean) * rstd * ga1.y + be1.y, 0.f);
    o.z = fmaxf((v1.z - mean) * rstd * ga1.z + be1.z, 0.f);
    o.w = fmaxf((v1.w - mean) * rstd * ga1.w + be1.w, 0.f);
    *(float4*)(hp + 4) = o;
  }
}

// ---- layer 1 GEMM: [32 nodes x 272] @ [272 x 64] + bias + LN (no atomics) ----
// 512 threads (8 waves): 2 nodes x 2 feats per thread.
__global__ __launch_bounds__(512, 6) void layer1_gemm(
    const float* __restrict__ hin, const float* __restrict__ SH,
    const float* __restrict__ SE, const float* __restrict__ deg,
    const float* __restrict__ Ws, const float* __restrict__ Wm,
    const float* __restrict__ bs, const float* __restrict__ bm,
    const float* __restrict__ gam, const float* __restrict__ bet,
    float* __restrict__ node_emb, int N) {
  __shared__ float u[32][UPAD];
  __shared__ float dgs[32], dinv[32];
  int tid = threadIdx.x;
  int n0 = blockIdx.x * 32;
  if (tid < 32) {
    int n = n0 + tid;
    float dg = (n < N) ? deg[n] : 0.f;
    dgs[tid] = dg;
    dinv[tid] = dg > 0.f ? 1.f / dg : 0.f;
  }
  __syncthreads();
  for (int idx = tid; idx < 1024; idx += 512) {
    int m = idx >> 5, f = (idx & 31) * 4;
    int n = n0 + m;
    float4 xv = make_float4(0.f, 0.f, 0.f, 0.f), sv = xv;
    if (n < N) {
      xv = *(const float4*)&hin[(size_t)n * 128 + f];
      sv = *(const float4*)&SH[(size_t)n * 128 + f];
      float di = dinv[m];
      sv.x *= di; sv.y *= di; sv.z *= di; sv.w *= di;
    }
    *(float4*)&u[m][f] = xv;
    *(float4*)&u[m][128 + f] = sv;
  }
  if (tid < 128) {
    int m = tid >> 2, f = (tid & 3) * 4;
    int n = n0 + m;
    float4 ev = make_float4(0.f, 0.f, 0.f, 0.f);
    if (n < N) {
      ev = *(const float4*)&SE[(size_t)n * 16 + f];
      float di = dinv[m];
      ev.x *= di; ev.y *= di; ev.z *= di; ev.w *= di;
    }
    *(float4*)&u[m][256 + f] = ev;
  }
  __syncthreads();

  int tn = tid >> 5;   // 0..15: node pair
  int tj = tid & 31;
  int jb = tj * 2;
  float2 bsv = *(const float2*)&bs[jb];
  float2 bmv = *(const float2*)&bm[jb];
  float acc[2][2];
  #pragma unroll
  for (int m = 0; m < 2; ++m) {
    bool has = dgs[tn * 2 + m] > 0.f;
    acc[m][0] = bsv.x + (has ? bmv.x : 0.f);
    acc[m][1] = bsv.y + (has ? bmv.y : 0.f);
  }

  #pragma unroll 2
  for (int k = 0; k < 128; k += 4) {
    float2 wv[4];
    float4 uv[2];
    #pragma unroll
    for (int t = 0; t < 4; ++t) wv[t] = *(const float2*)&Ws[(size_t)(k + t) * 64 + jb];
    #pragma unroll
    for (int m = 0; m < 2; ++m) uv[m] = *(const float4*)&u[tn * 2 + m][k];
    #pragma unroll
    for (int m = 0; m < 2; ++m) {
      float us[4] = {uv[m].x, uv[m].y, uv[m].z, uv[m].w};
      #pragma unroll
      for (int t = 0; t < 4; ++t) {
        acc[m][0] = fmaf(us[t], wv[t].x, acc[m][0]);
        acc[m][1] = fmaf(us[t], wv[t].y, acc[m][1]);
      }
    }
  }
  #pragma unroll 2
  for (int k = 0; k < 144; k += 4) {
    float2 wv[4];
    float4 uv[2];
    #pragma unroll
    for (int t = 0; t < 4; ++t) wv[t] = *(const float2*)&Wm[(size_t)(k + t) * 64 + jb];
    #pragma unroll
    for (int m = 0; m < 2; ++m) uv[m] = *(const float4*)&u[tn * 2 + m][128 + k];
    #pragma unroll
    for (int m = 0; m < 2; ++m) {
      float us[4] = {uv[m].x, uv[m].y, uv[m].z, uv[m].w};
      #pragma unroll
      for (int t = 0; t < 4; ++t) {
        acc[m][0] = fmaf(us[t], wv[t].x, acc[m][0]);
        acc[m][1] = fmaf(us[t], wv[t].y, acc[m][1]);
      }
    }
  }

  __syncthreads();
  #pragma unroll
  for (int m = 0; m < 2; ++m)
    *(float2*)&u[tn * 2 + m][jb] = make_float2(acc[m][0], acc[m][1]);
  __syncthreads();

  // LN: 16 threads per node, 4 feats each
  int node = tid >> 4, s = tid & 15;
  int fb = s * 4;
  float4 v0 = *(const float4*)&u[node][fb];
  float sum = v0.x + v0.y + v0.z + v0.w;
  float sq  = v0.x*v0.x + v0.y*v0.y + v0.z*v0.z + v0.w*v0.w;
  #pragma unroll
  for (int off = 1; off < 16; off <<= 1) {
    sum += __shfl_xor(sum, off);
    sq  += __shfl_xor(sq, off);
  }
  float mean = sum * (1.f / 64.f);
  float var  = sq * (1.f / 64.f) - mean * mean;
  float rstd = rsqrtf(var + LN_EPS);
  int n = n0 + node;
  if (n < N) {
    float4 ga0 = *(const float4*)&gam[fb];
    float4 be0 = *(const float4*)&bet[fb];
    float4 o0;
    o0.x = (v0.x - mean) * rstd * ga0.x + be0.x;
    o0.y = (v0.y - mean) * rstd * ga0.y + be0.y;
    o0.z = (v0.z - mean) * rstd * ga0.z + be0.z;
    o0.w = (v0.w - mean) * rstd * ga0.w + be0.w;
    *(float4*)&node_emb[(size_t)n * 64 + fb] = o0;
  }
}

// ---- graph pooling: batch is sorted; block g segment-sums node_emb[lo:hi) ----
__global__ __launch_bounds__(256) void graph_pool(
    const float* __restrict__ node_emb, const int* __restrict__ batch,
    float* __restrict__ out, int N) {
  __shared__ float red[4][64];
  int g = blockIdx.x;
  int tid = threadIdx.x;
  int j = tid & 63, c = tid >> 6;
  int lo = 0, hi = N;
  while (lo < hi) { int mid = (lo + hi) >> 1; if (batch[mid] < g) lo = mid + 1; else hi = mid; }
  int start = lo;
  lo = 0; hi = N;
  while (lo < hi) { int mid = (lo + hi) >> 1; if (batch[mid] < g + 1) lo = mid + 1; else hi = mid; }
  int end = lo;
  float s = 0.f;
  for (int n = start + c; n < end; n += 4)
    s += node_emb[(size_t)n * 64 + j];
  red[c][j] = s;
  __syncthreads();
  if (c == 0) {
    float tot = red[0][j] + red[1][j] + red[2][j] + red[3][j];
    float inv = 1.f / fmaxf((float)(end - start), 1.f);
    out[g * 64 + j] = tot * inv;
  }
}

extern "C" void kernel_launch(void* const* d_in, const int* in_sizes, int n_in,
                              void* d_out, int out_size, void* d_ws, size_t ws_size,
                              hipStream_t stream) {
  const float* x   = (const float*)d_in[0];
  const float* ef  = (const float*)d_in[1];
  const float* Ws0 = (const float*)d_in[2];
  const float* bs0 = (const float*)d_in[3];
  const float* Wm0 = (const float*)d_in[4];
  const float* bm0 = (const float*)d_in[5];
  const float* g0  = (const float*)d_in[6];
  const float* be0 = (const float*)d_in[7];
  const float* Ws1 = (const float*)d_in[8];
  const float* bs1 = (const float*)d_in[9];
  const float* Wm1 = (const float*)d_in[10];
  const float* bm1 = (const float*)d_in[11];
  const float* g1  = (const float*)d_in[12];
  const float* be1 = (const float*)d_in[13];
  const int* edge_index = (const int*)d_in[14];
  const int* batch = (const int*)d_in[15];

  const int N = in_sizes[0] / 128;
  const int E = in_sizes[14] / 2;
  const int G = 64;
  const int* src = edge_index;
  const int* tgt = edge_index + E;

  char* ws = (char*)d_ws;
  size_t off = 0;
  auto alloc = [&](size_t bytes) -> void* {
    void* p = ws + off;
    off = (off + bytes + 255) & ~(size_t)255;
    return p;
  };
  float* SX     = (float*)alloc((size_t)N * 128 * 4);  // reused as SH for layer 1
  float* SE     = (float*)alloc((size_t)N * 16 * 4);
  float* deg    = (float*)alloc((size_t)N * 4);
  float* h      = (float*)alloc((size_t)N * 128 * 4);
  int*   cnt    = (int*)alloc((size_t)N * 4);          // reused as cursor for fill
  int*   rowptr = (int*)alloc((size_t)(N + 1) * 4);
  int2*  csr    = (int2*)alloc((size_t)E * 8);

  hipMemsetAsync(cnt, 0, (size_t)N * 4, stream);

  hist_tgt<<<(E + 255) / 256, 256, 0, stream>>>(tgt, cnt, E);
  scan_rowptr<<<1, 1024, 0, stream>>>(cnt, rowptr, N);
  hipMemsetAsync(cnt, 0, (size_t)N * 4, stream);  // reuse as fill cursor
  fill_csr<<<(E + 255) / 256, 256, 0, stream>>>(src, tgt, rowptr, cnt, csr, E);

  agg0<<<(N + 3) / 4, 256, 0, stream>>>(x, ef, rowptr, csr, SX, SE, deg, N);

  layer0_gemm<<<(N + 31) / 32, 512, 0, stream>>>(
      x, SX, SE, deg, Ws0, Wm0, bs0, bm0, g0, be0, h, N);

  agg1<<<(N + 3) / 4, 256, 0, stream>>>(h, rowptr, csr, SX, N);

  layer1_gemm<<<(N + 31) / 32, 512, 0, stream>>>(
      h, SX, SE, deg, Ws1, Wm1, bs1, bm1, g1, be1, (float*)d_out, N);

  graph_pool<<<G, 256, 0, stream>>>((const float*)d_out, batch,
                                    (float*)d_out + (size_t)N * 64, N);
}